// Round 4
// baseline (1135.164 us; speedup 1.0000x reference)
//
#include <hip/hip_runtime.h>

// ---------------------------------------------------------------------------
// MoE forward (top-2 of 8 experts), sparse-routed, bf16 MFMA.
// Round 4 = round-2 GEMM bodies (reg-staged, padded LDS, high occupancy)
//         + round-3 grid order (row-block fastest -> weight-tile L2 reuse).
// ---------------------------------------------------------------------------

typedef __bf16 bf16x8 __attribute__((ext_vector_type(8)));
typedef float f32x4 __attribute__((ext_vector_type(4)));
typedef unsigned short us8 __attribute__((ext_vector_type(8)));

#define T_TOK 8192
#define DIMD 1024
#define NEXP 8
#define HID 2730
#define HPAD 2752
#define H2PAD 5504
#define NPAIR 16384

#define WS_CTRL  ((size_t)0)
#define WS_TOPI  ((size_t)256)
#define WS_TOPW  (WS_TOPI + 65536)
#define WS_POS   (WS_TOPW + 65536)
#define WS_PTOK  (WS_POS + 65536)
#define WS_XB    (WS_PTOK + 65536)
#define WS_W12T  (WS_XB + (size_t)16777216)
#define WS_W3T   (WS_W12T + (size_t)90177536)
#define WS_HBUF  (WS_W3T + (size_t)45088768)
#define WS_POUT  (WS_HBUF + (size_t)90177536)

__device__ __forceinline__ unsigned short f2bf(float f) {
    unsigned int u = __float_as_uint(f);
    u += 0x7fffu + ((u >> 16) & 1u);
    return (unsigned short)(u >> 16);
}

// ---------------- x -> bf16 ----------------
__global__ void k_cvt_x(const float4* __restrict__ x, ushort4* __restrict__ xb) {
    const int total = T_TOK * DIMD / 4;
    for (int i = blockIdx.x * 256 + threadIdx.x; i < total; i += gridDim.x * 256) {
        float4 v = x[i];
        ushort4 r;
        r.x = f2bf(v.x); r.y = f2bf(v.y); r.z = f2bf(v.z); r.w = f2bf(v.w);
        xb[i] = r;
    }
}

// ---------------- W12 -> bf16, transposed [e][half][jp(2752)][k(1024)] ------
__global__ void k_cvt_w12t(const float* __restrict__ w12, unsigned short* __restrict__ w12t) {
    int jt = blockIdx.x;             // 0..85
    int kt = blockIdx.y;             // 0..31
    int e  = blockIdx.z;
    int half = jt / 43, jt2 = jt % 43;
    int jh0 = jt2 * 64, k0 = kt * 32;
    __shared__ float tile[32][65];
    int t = threadIdx.x;
    {
        int kk = t >> 3, jq = t & 7;
        const float* src = w12 + (size_t)(e * 1024 + k0 + kk) * 5460 + half * HID;
#pragma unroll
        for (int m = 0; m < 4; ++m) {
            int jj = jq * 8 + m * 2;
            int jh = jh0 + jj;
            float2 v = make_float2(0.f, 0.f);
            if (jh < HID) v = *(const float2*)(src + jh);
            tile[kk][jj] = v.x; tile[kk][jj + 1] = v.y;
        }
    }
    __syncthreads();
    {
        int jj = t & 63, kq = t >> 6;
        us8 v;
#pragma unroll
        for (int b = 0; b < 8; ++b) v[b] = f2bf(tile[kq * 8 + b][jj]);
        *(us8*)(w12t + ((size_t)e * H2PAD + half * HPAD + jh0 + jj) * 1024 + k0 + kq * 8) = v;
    }
}

// ---------------- W3 -> bf16, transposed [e][d(1024)][k(2752)] --------------
__global__ void k_cvt_w3t(const float* __restrict__ w3, unsigned short* __restrict__ w3t) {
    int kt = blockIdx.x;             // 0..85
    int dt = blockIdx.y;             // 0..15
    int e  = blockIdx.z;
    int k0 = kt * 32, d0 = dt * 64;
    __shared__ float tile[32][65];
    int t = threadIdx.x;
    {
        int kk = t >> 3, dq = t & 7;
        bool kv = (k0 + kk) < HID;
        const float* src = w3 + ((size_t)e * HID + k0 + kk) * 1024 + d0;
#pragma unroll
        for (int m = 0; m < 2; ++m) {
            int dd = dq * 8 + m * 4;
            float4 v = make_float4(0.f, 0.f, 0.f, 0.f);
            if (kv) v = *(const float4*)(src + dd);
            tile[kk][dd] = v.x; tile[kk][dd + 1] = v.y; tile[kk][dd + 2] = v.z; tile[kk][dd + 3] = v.w;
        }
    }
    __syncthreads();
    {
        int dd = t & 63, kq = t >> 6;
        us8 v;
#pragma unroll
        for (int b = 0; b < 8; ++b) v[b] = f2bf(tile[kq * 8 + b][dd]);
        *(us8*)(w3t + ((size_t)e * 1024 + d0 + dd) * HPAD + k0 + kq * 8) = v;
    }
}

// ---------------- router: fp64 logits, stable top-2, softmax, counts --------
__global__ void k_router(const float* __restrict__ x, const float* __restrict__ wr,
                         int* __restrict__ topi, float* __restrict__ topw,
                         int* __restrict__ ctrl) {
    int wid = threadIdx.x >> 6, lane = threadIdx.x & 63;
    int t = blockIdx.x * 4 + wid;
    const float* xr = x + (size_t)t * DIMD;
    double acc[NEXP];
#pragma unroll
    for (int e = 0; e < NEXP; ++e) acc[e] = 0.0;
    for (int d = lane; d < DIMD; d += 64) {
        double xv = (double)xr[d];
        const float* w = wr + d * NEXP;
#pragma unroll
        for (int e = 0; e < NEXP; ++e) acc[e] += xv * (double)w[e];
    }
#pragma unroll
    for (int e = 0; e < NEXP; ++e) {
        for (int off = 32; off > 0; off >>= 1) acc[e] += __shfl_down(acc[e], off);
    }
    if (lane == 0) {
        double b0 = -1e300, b1 = -1e300; int i0 = 0, i1 = 0;
#pragma unroll
        for (int e = 0; e < NEXP; ++e) {
            double v = acc[e];
            if (v > b0) { b1 = b0; i1 = i0; b0 = v; i0 = e; }
            else if (v > b1) { b1 = v; i1 = e; }
        }
        float e1 = expf((float)(b1 - b0));
        float w0 = 1.0f / (1.0f + e1);
        float w1 = e1 / (1.0f + e1);
        topi[2 * t] = i0; topi[2 * t + 1] = i1;
        topw[2 * t] = w0; topw[2 * t + 1] = w1;
        atomicAdd(&ctrl[i0], 1);
        atomicAdd(&ctrl[i1], 1);
    }
}

__global__ void k_scan(int* ctrl) {
    if (threadIdx.x == 0 && blockIdx.x == 0) {
        int s = 0;
        for (int e = 0; e < NEXP; ++e) { ctrl[16 + e] = s; s += ctrl[e]; }
        ctrl[16 + NEXP] = s;
    }
}

__global__ void k_compact(const int* __restrict__ topi, int* __restrict__ ctrl,
                          int* __restrict__ ptok, int* __restrict__ pos) {
    int t = blockIdx.x * 256 + threadIdx.x;
    if (t >= T_TOK) return;
#pragma unroll
    for (int k = 0; k < 2; ++k) {
        int e = topi[2 * t + k];
        int p = ctrl[16 + e] + atomicAdd(&ctrl[8 + e], 1);
        ptok[p] = t;
        pos[2 * t + k] = p;
    }
}

// ---------------- GEMM1 + GLU: h = silu(x@W1)*(x@W2), bf16 out --------------
// block: 128 rows x 64 h-cols (both halves), BK=32, 4 waves (2m x 2n)
// grid: x = row-block (fastest, shares B tile), y = j-tile(43), z = expert
__global__ __launch_bounds__(256, 2) void k_gemm1(
    const unsigned short* __restrict__ xb,
    const unsigned short* __restrict__ w12t,
    const int* __restrict__ ctrl,
    const int* __restrict__ ptok,
    unsigned short* __restrict__ hbuf) {
    int e = blockIdx.z;
    int n_e = ctrl[e];
    int r0 = blockIdx.x * 128;
    if (r0 >= n_e) return;
    int p0 = ctrl[16 + e] + r0;
    int j0 = blockIdx.y * 64;

    __shared__ unsigned short Al[128][40];
    __shared__ unsigned short Bl[2][64][40];
    __shared__ int stok[128];

    int tid = threadIdx.x;
    if (tid < 128) {
        stok[tid] = (r0 + tid < n_e) ? ptok[p0 + tid] : 0;
    }
    __syncthreads();

    int lane = tid & 63, wid = tid >> 6;
    int wm = wid >> 1, wn = wid & 1;
    int lr = lane & 15, lk = lane >> 4;

    f32x4 acc[2][4][2];
#pragma unroll
    for (int h = 0; h < 2; ++h)
#pragma unroll
        for (int m = 0; m < 4; ++m)
#pragma unroll
            for (int n = 0; n < 2; ++n) acc[h][m][n] = (f32x4){0.f, 0.f, 0.f, 0.f};

    int arow = tid >> 1, as0 = (tid & 1) * 16;
    const unsigned short* abase = xb + (size_t)stok[arow] * DIMD;
    int bhjj = tid >> 1;
    int bh = bhjj >> 6, bjj = bhjj & 63, bs0 = (tid & 1) * 16;
    const unsigned short* bbase = w12t + ((size_t)e * H2PAD + bh * HPAD + j0 + bjj) * 1024;

#pragma unroll 1
    for (int k0 = 0; k0 < DIMD; k0 += 32) {
        us8 a0 = *(const us8*)(abase + k0 + as0);
        us8 a1 = *(const us8*)(abase + k0 + as0 + 8);
        us8 b0 = *(const us8*)(bbase + k0 + bs0);
        us8 b1 = *(const us8*)(bbase + k0 + bs0 + 8);
        __syncthreads();
        *(us8*)&Al[arow][as0] = a0;
        *(us8*)&Al[arow][as0 + 8] = a1;
        *(us8*)&Bl[bh][bjj][bs0] = b0;
        *(us8*)&Bl[bh][bjj][bs0 + 8] = b1;
        __syncthreads();
        bf16x8 af[4];
#pragma unroll
        for (int m = 0; m < 4; ++m)
            af[m] = *(const bf16x8*)&Al[wm * 64 + m * 16 + lr][lk * 8];
        bf16x8 bf_[2][2];
#pragma unroll
        for (int h = 0; h < 2; ++h)
#pragma unroll
            for (int n = 0; n < 2; ++n)
                bf_[h][n] = *(const bf16x8*)&Bl[h][wn * 32 + n * 16 + lr][lk * 8];
#pragma unroll
        for (int h = 0; h < 2; ++h)
#pragma unroll
            for (int m = 0; m < 4; ++m)
#pragma unroll
                for (int n = 0; n < 2; ++n)
                    acc[h][m][n] = __builtin_amdgcn_mfma_f32_16x16x32_bf16(
                        af[m], bf_[h][n], acc[h][m][n], 0, 0, 0);
    }

#pragma unroll
    for (int m = 0; m < 4; ++m)
#pragma unroll
        for (int n = 0; n < 2; ++n)
#pragma unroll
            for (int q = 0; q < 4; ++q) {
                int rl = wm * 64 + m * 16 + lk * 4 + q;
                if (r0 + rl < n_e) {
                    float v1 = acc[0][m][n][q];
                    float v2 = acc[1][m][n][q];
                    float hv = v1 * (1.0f / (1.0f + __expf(-v1))) * v2;
                    hbuf[(size_t)(p0 + rl) * HPAD + (j0 + wn * 32 + n * 16 + lr)] = f2bf(hv);
                }
            }
}

// ---------------- GEMM2: eo = h @ W3  -> pout (f32) -------------------------
// block: 128 rows x 128 d-cols, BK=32, 4 waves (2m x 2n), K=2752 padded
// grid: x = row-block (fastest), y = d-tile(8), z = expert
__global__ __launch_bounds__(256, 2) void k_gemm2(
    const unsigned short* __restrict__ hbuf,
    const unsigned short* __restrict__ w3t,
    const int* __restrict__ ctrl,
    float* __restrict__ pout) {
    int e = blockIdx.z;
    int n_e = ctrl[e];
    int r0 = blockIdx.x * 128;
    if (r0 >= n_e) return;
    int p0 = ctrl[16 + e] + r0;
    int d0 = blockIdx.y * 128;

    __shared__ unsigned short Al[128][40];
    __shared__ unsigned short Bl[128][40];

    int tid = threadIdx.x;
    int lane = tid & 63, wid = tid >> 6;
    int wm = wid >> 1, wn = wid & 1;
    int lr = lane & 15, lk = lane >> 4;

    f32x4 acc[4][4];
#pragma unroll
    for (int m = 0; m < 4; ++m)
#pragma unroll
        for (int n = 0; n < 4; ++n) acc[m][n] = (f32x4){0.f, 0.f, 0.f, 0.f};

    int arow = tid >> 1, as0 = (tid & 1) * 16;
    int arr = (r0 + arow < n_e) ? arow : 0;
    const unsigned short* abase = hbuf + (size_t)(p0 + arr) * HPAD;
    int brow = tid >> 1, bs0 = (tid & 1) * 16;
    const unsigned short* bbase = w3t + ((size_t)e * 1024 + d0 + brow) * HPAD;

#pragma unroll 1
    for (int k0 = 0; k0 < HPAD; k0 += 32) {
        us8 a0 = *(const us8*)(abase + k0 + as0);
        us8 a1 = *(const us8*)(abase + k0 + as0 + 8);
        us8 b0 = *(const us8*)(bbase + k0 + bs0);
        us8 b1 = *(const us8*)(bbase + k0 + bs0 + 8);
        __syncthreads();
        *(us8*)&Al[arow][as0] = a0;
        *(us8*)&Al[arow][as0 + 8] = a1;
        *(us8*)&Bl[brow][bs0] = b0;
        *(us8*)&Bl[brow][bs0 + 8] = b1;
        __syncthreads();
        bf16x8 af[4], bf_[4];
#pragma unroll
        for (int m = 0; m < 4; ++m)
            af[m] = *(const bf16x8*)&Al[wm * 64 + m * 16 + lr][lk * 8];
#pragma unroll
        for (int n = 0; n < 4; ++n)
            bf_[n] = *(const bf16x8*)&Bl[wn * 64 + n * 16 + lr][lk * 8];
#pragma unroll
        for (int m = 0; m < 4; ++m)
#pragma unroll
            for (int n = 0; n < 4; ++n)
                acc[m][n] = __builtin_amdgcn_mfma_f32_16x16x32_bf16(
                    af[m], bf_[n], acc[m][n], 0, 0, 0);
    }

#pragma unroll
    for (int m = 0; m < 4; ++m)
#pragma unroll
        for (int n = 0; n < 4; ++n)
#pragma unroll
            for (int q = 0; q < 4; ++q) {
                int rl = wm * 64 + m * 16 + lk * 4 + q;
                if (r0 + rl < n_e) {
                    pout[(size_t)(p0 + rl) * DIMD + (d0 + wn * 64 + n * 16 + lr)] = acc[m][n][q];
                }
            }
}

// ---------------- combine: out[t] = w0*eo[p0] + w1*eo[p1] -------------------
__global__ void k_combine(const float4* __restrict__ pout, const int* __restrict__ pos,
                          const float* __restrict__ topw, float4* __restrict__ out) {
    int idx = blockIdx.x * 256 + threadIdx.x;
    int tok = idx >> 8, c = idx & 255;
    int p0 = pos[2 * tok], p1 = pos[2 * tok + 1];
    float w0 = topw[2 * tok], w1 = topw[2 * tok + 1];
    float4 a = pout[(size_t)p0 * 256 + c];
    float4 b = pout[(size_t)p1 * 256 + c];
    float4 r;
    r.x = w0 * a.x + w1 * b.x;
    r.y = w0 * a.y + w1 * b.y;
    r.z = w0 * a.z + w1 * b.z;
    r.w = w0 * a.w + w1 * b.w;
    out[idx] = r;
}

extern "C" void kernel_launch(void* const* d_in, const int* in_sizes, int n_in,
                              void* d_out, int out_size, void* d_ws, size_t ws_size,
                              hipStream_t stream) {
    const float* x   = (const float*)d_in[0];
    const float* wr  = (const float*)d_in[1];
    const float* w12 = (const float*)d_in[2];
    const float* w3  = (const float*)d_in[3];
    float* out = (float*)d_out;

    char* ws = (char*)d_ws;
    int*            ctrl = (int*)(ws + WS_CTRL);
    int*            topi = (int*)(ws + WS_TOPI);
    float*          topw = (float*)(ws + WS_TOPW);
    int*            pos  = (int*)(ws + WS_POS);
    int*            ptok = (int*)(ws + WS_PTOK);
    unsigned short* xb   = (unsigned short*)(ws + WS_XB);
    unsigned short* w12t = (unsigned short*)(ws + WS_W12T);
    unsigned short* w3t  = (unsigned short*)(ws + WS_W3T);
    unsigned short* hbuf = (unsigned short*)(ws + WS_HBUF);
    float*          pout = (float*)(ws + WS_POUT);

    (void)ws_size; (void)in_sizes; (void)n_in; (void)out_size;

    (void)hipMemsetAsync(ctrl, 0, 256, stream);
    k_cvt_x<<<2048, 256, 0, stream>>>((const float4*)x, (ushort4*)xb);
    k_cvt_w12t<<<dim3(86, 32, 8), 256, 0, stream>>>(w12, w12t);
    k_cvt_w3t<<<dim3(86, 16, 8), 256, 0, stream>>>(w3, w3t);
    k_router<<<2048, 256, 0, stream>>>(x, wr, topi, topw, ctrl);
    k_scan<<<1, 64, 0, stream>>>(ctrl);
    k_compact<<<32, 256, 0, stream>>>(topi, ctrl, ptok, pos);
    k_gemm1<<<dim3(64, 43, 8), 256, 0, stream>>>(xb, w12t, ctrl, ptok, hbuf);
    k_gemm2<<<dim3(64, 8, 8), 256, 0, stream>>>(hbuf, w3t, ctrl, pout);
    k_combine<<<8192, 256, 0, stream>>>((const float4*)pout, pos, topw, (float4*)out);
}

// Round 5
// 940.682 us; speedup vs baseline: 1.2067x; 1.2067x over previous
//
#include <hip/hip_runtime.h>

// ---------------------------------------------------------------------------
// MoE forward (top-2 of 8 experts), sparse-routed, bf16 MFMA.
// Round 5 = round-2 GEMM bodies + round-2 grid order (proven 307us gemm1)
//         + combine fused into gemm2 epilogue (gated atomicAdd, deterministic:
//           exactly 2 commutative f32 addends per output element)
//         + x->bf16 conversion fused into router.
// ---------------------------------------------------------------------------

typedef __bf16 bf16x8 __attribute__((ext_vector_type(8)));
typedef float f32x4 __attribute__((ext_vector_type(4)));
typedef unsigned short us8 __attribute__((ext_vector_type(8)));

#define T_TOK 8192
#define DIMD 1024
#define NEXP 8
#define HID 2730
#define HPAD 2752
#define H2PAD 5504
#define NPAIR 16384

#define WS_CTRL  ((size_t)0)
#define WS_TOPI  ((size_t)256)
#define WS_TOPW  (WS_TOPI + 65536)
#define WS_PW    (WS_TOPW + 65536)
#define WS_PTOK  (WS_PW + 65536)
#define WS_XB    (WS_PTOK + 65536)
#define WS_W12T  (WS_XB + (size_t)16777216)
#define WS_W3T   (WS_W12T + (size_t)90177536)
#define WS_HBUF  (WS_W3T + (size_t)45088768)

__device__ __forceinline__ unsigned short f2bf(float f) {
    unsigned int u = __float_as_uint(f);
    u += 0x7fffu + ((u >> 16) & 1u);
    return (unsigned short)(u >> 16);
}

// ---------------- W12 -> bf16, transposed [e][half][jp(2752)][k(1024)] ------
__global__ void k_cvt_w12t(const float* __restrict__ w12, unsigned short* __restrict__ w12t) {
    int jt = blockIdx.x;             // 0..85
    int kt = blockIdx.y;             // 0..31
    int e  = blockIdx.z;
    int half = jt / 43, jt2 = jt % 43;
    int jh0 = jt2 * 64, k0 = kt * 32;
    __shared__ float tile[32][65];
    int t = threadIdx.x;
    {
        int kk = t >> 3, jq = t & 7;
        const float* src = w12 + (size_t)(e * 1024 + k0 + kk) * 5460 + half * HID;
#pragma unroll
        for (int m = 0; m < 4; ++m) {
            int jj = jq * 8 + m * 2;
            int jh = jh0 + jj;
            float2 v = make_float2(0.f, 0.f);
            if (jh < HID) v = *(const float2*)(src + jh);
            tile[kk][jj] = v.x; tile[kk][jj + 1] = v.y;
        }
    }
    __syncthreads();
    {
        int jj = t & 63, kq = t >> 6;
        us8 v;
#pragma unroll
        for (int b = 0; b < 8; ++b) v[b] = f2bf(tile[kq * 8 + b][jj]);
        *(us8*)(w12t + ((size_t)e * H2PAD + half * HPAD + jh0 + jj) * 1024 + k0 + kq * 8) = v;
    }
}

// ---------------- W3 -> bf16, transposed [e][d(1024)][k(2752)] --------------
__global__ void k_cvt_w3t(const float* __restrict__ w3, unsigned short* __restrict__ w3t) {
    int kt = blockIdx.x;             // 0..85
    int dt = blockIdx.y;             // 0..15
    int e  = blockIdx.z;
    int k0 = kt * 32, d0 = dt * 64;
    __shared__ float tile[32][65];
    int t = threadIdx.x;
    {
        int kk = t >> 3, dq = t & 7;
        bool kv = (k0 + kk) < HID;
        const float* src = w3 + ((size_t)e * HID + k0 + kk) * 1024 + d0;
#pragma unroll
        for (int m = 0; m < 2; ++m) {
            int dd = dq * 8 + m * 4;
            float4 v = make_float4(0.f, 0.f, 0.f, 0.f);
            if (kv) v = *(const float4*)(src + dd);
            tile[kk][dd] = v.x; tile[kk][dd + 1] = v.y; tile[kk][dd + 2] = v.z; tile[kk][dd + 3] = v.w;
        }
    }
    __syncthreads();
    {
        int dd = t & 63, kq = t >> 6;
        us8 v;
#pragma unroll
        for (int b = 0; b < 8; ++b) v[b] = f2bf(tile[kq * 8 + b][dd]);
        *(us8*)(w3t + ((size_t)e * 1024 + d0 + dd) * HPAD + k0 + kq * 8) = v;
    }
}

// ---------------- router (fused x->bf16): fp64 logits, stable top-2 ---------
__global__ void k_router(const float4* __restrict__ x4, const float* __restrict__ wr,
                         ushort4* __restrict__ xb4,
                         int* __restrict__ topi, float* __restrict__ topw,
                         int* __restrict__ ctrl) {
    int wid = threadIdx.x >> 6, lane = threadIdx.x & 63;
    int t = blockIdx.x * 4 + wid;
    const float4* xr = x4 + (size_t)t * 256;
    double acc[NEXP];
#pragma unroll
    for (int e = 0; e < NEXP; ++e) acc[e] = 0.0;
#pragma unroll
    for (int it = 0; it < 4; ++it) {
        int d4 = it * 64 + lane;             // float4 index within row
        float4 v = xr[d4];
        ushort4 r;
        r.x = f2bf(v.x); r.y = f2bf(v.y); r.z = f2bf(v.z); r.w = f2bf(v.w);
        xb4[(size_t)t * 256 + d4] = r;
        const float* w = wr + (size_t)d4 * 4 * NEXP;
#pragma unroll
        for (int e = 0; e < NEXP; ++e) {
            acc[e] += (double)v.x * (double)w[e]
                    + (double)v.y * (double)w[NEXP + e]
                    + (double)v.z * (double)w[2 * NEXP + e]
                    + (double)v.w * (double)w[3 * NEXP + e];
        }
    }
#pragma unroll
    for (int e = 0; e < NEXP; ++e) {
        for (int off = 32; off > 0; off >>= 1) acc[e] += __shfl_down(acc[e], off);
    }
    if (lane == 0) {
        double b0 = -1e300, b1 = -1e300; int i0 = 0, i1 = 0;
#pragma unroll
        for (int e = 0; e < NEXP; ++e) {
            double v = acc[e];
            if (v > b0) { b1 = b0; i1 = i0; b0 = v; i0 = e; }
            else if (v > b1) { b1 = v; i1 = e; }
        }
        float e1 = expf((float)(b1 - b0));
        float w0 = 1.0f / (1.0f + e1);
        float w1 = e1 / (1.0f + e1);
        topi[2 * t] = i0; topi[2 * t + 1] = i1;
        topw[2 * t] = w0; topw[2 * t + 1] = w1;
        atomicAdd(&ctrl[i0], 1);
        atomicAdd(&ctrl[i1], 1);
    }
}

__global__ void k_scan(int* ctrl) {
    if (threadIdx.x == 0 && blockIdx.x == 0) {
        int s = 0;
        for (int e = 0; e < NEXP; ++e) { ctrl[16 + e] = s; s += ctrl[e]; }
        ctrl[16 + NEXP] = s;
    }
}

__global__ void k_compact(const int* __restrict__ topi, const float* __restrict__ topw,
                          int* __restrict__ ctrl,
                          int* __restrict__ ptok, float* __restrict__ pw) {
    int t = blockIdx.x * 256 + threadIdx.x;
    if (t >= T_TOK) return;
#pragma unroll
    for (int k = 0; k < 2; ++k) {
        int e = topi[2 * t + k];
        int p = ctrl[16 + e] + atomicAdd(&ctrl[8 + e], 1);
        ptok[p] = t;
        pw[p] = topw[2 * t + k];
    }
}

// ---------------- GEMM1 + GLU: h = silu(x@W1)*(x@W2), bf16 out --------------
// block: 128 rows x 64 h-cols (both halves), BK=32, 4 waves (2m x 2n)
// grid: x = j-tile(43) FASTEST (A-rows stay hot; B streams at HBM BW — the
//       empirically-proven order, r2: 307us vs r4 row-fastest: 465us)
__global__ __launch_bounds__(256, 2) void k_gemm1(
    const unsigned short* __restrict__ xb,
    const unsigned short* __restrict__ w12t,
    const int* __restrict__ ctrl,
    const int* __restrict__ ptok,
    unsigned short* __restrict__ hbuf) {
    int e = blockIdx.z;
    int n_e = ctrl[e];
    int r0 = blockIdx.y * 128;
    if (r0 >= n_e) return;
    int p0 = ctrl[16 + e] + r0;
    int j0 = blockIdx.x * 64;

    __shared__ unsigned short Al[128][40];
    __shared__ unsigned short Bl[2][64][40];
    __shared__ int stok[128];

    int tid = threadIdx.x;
    if (tid < 128) {
        stok[tid] = (r0 + tid < n_e) ? ptok[p0 + tid] : 0;
    }
    __syncthreads();

    int lane = tid & 63, wid = tid >> 6;
    int wm = wid >> 1, wn = wid & 1;
    int lr = lane & 15, lk = lane >> 4;

    f32x4 acc[2][4][2];
#pragma unroll
    for (int h = 0; h < 2; ++h)
#pragma unroll
        for (int m = 0; m < 4; ++m)
#pragma unroll
            for (int n = 0; n < 2; ++n) acc[h][m][n] = (f32x4){0.f, 0.f, 0.f, 0.f};

    int arow = tid >> 1, as0 = (tid & 1) * 16;
    const unsigned short* abase = xb + (size_t)stok[arow] * DIMD;
    int bhjj = tid >> 1;
    int bh = bhjj >> 6, bjj = bhjj & 63, bs0 = (tid & 1) * 16;
    const unsigned short* bbase = w12t + ((size_t)e * H2PAD + bh * HPAD + j0 + bjj) * 1024;

#pragma unroll 1
    for (int k0 = 0; k0 < DIMD; k0 += 32) {
        us8 a0 = *(const us8*)(abase + k0 + as0);
        us8 a1 = *(const us8*)(abase + k0 + as0 + 8);
        us8 b0 = *(const us8*)(bbase + k0 + bs0);
        us8 b1 = *(const us8*)(bbase + k0 + bs0 + 8);
        __syncthreads();
        *(us8*)&Al[arow][as0] = a0;
        *(us8*)&Al[arow][as0 + 8] = a1;
        *(us8*)&Bl[bh][bjj][bs0] = b0;
        *(us8*)&Bl[bh][bjj][bs0 + 8] = b1;
        __syncthreads();
        bf16x8 af[4];
#pragma unroll
        for (int m = 0; m < 4; ++m)
            af[m] = *(const bf16x8*)&Al[wm * 64 + m * 16 + lr][lk * 8];
        bf16x8 bf_[2][2];
#pragma unroll
        for (int h = 0; h < 2; ++h)
#pragma unroll
            for (int n = 0; n < 2; ++n)
                bf_[h][n] = *(const bf16x8*)&Bl[h][wn * 32 + n * 16 + lr][lk * 8];
#pragma unroll
        for (int h = 0; h < 2; ++h)
#pragma unroll
            for (int m = 0; m < 4; ++m)
#pragma unroll
                for (int n = 0; n < 2; ++n)
                    acc[h][m][n] = __builtin_amdgcn_mfma_f32_16x16x32_bf16(
                        af[m], bf_[h][n], acc[h][m][n], 0, 0, 0);
    }

#pragma unroll
    for (int m = 0; m < 4; ++m)
#pragma unroll
        for (int n = 0; n < 2; ++n)
#pragma unroll
            for (int q = 0; q < 4; ++q) {
                int rl = wm * 64 + m * 16 + lk * 4 + q;
                if (r0 + rl < n_e) {
                    float v1 = acc[0][m][n][q];
                    float v2 = acc[1][m][n][q];
                    float hv = v1 * (1.0f / (1.0f + __expf(-v1))) * v2;
                    hbuf[(size_t)(p0 + rl) * HPAD + (j0 + wn * 32 + n * 16 + lr)] = f2bf(hv);
                }
            }
}

// ---------------- GEMM2 + gated scatter-add: out[tok] += w * (h @ W3) -------
// block: 128 rows x 128 d-cols, BK=32, 4 waves (2m x 2n), K=2752 padded
// grid: x = d-tile(8) fastest, y = row-block, z = expert (round-2 order)
// Epilogue: atomicAdd f32 into out — exactly 2 addends per element,
// f32 add commutative -> bitwise deterministic given zeroed out.
__global__ __launch_bounds__(256, 2) void k_gemm2(
    const unsigned short* __restrict__ hbuf,
    const unsigned short* __restrict__ w3t,
    const int* __restrict__ ctrl,
    const int* __restrict__ ptok,
    const float* __restrict__ pw,
    float* __restrict__ out) {
    int e = blockIdx.z;
    int n_e = ctrl[e];
    int r0 = blockIdx.y * 128;
    if (r0 >= n_e) return;
    int p0 = ctrl[16 + e] + r0;
    int d0 = blockIdx.x * 128;

    __shared__ unsigned short Al[128][40];
    __shared__ unsigned short Bl[128][40];

    int tid = threadIdx.x;
    int lane = tid & 63, wid = tid >> 6;
    int wm = wid >> 1, wn = wid & 1;
    int lr = lane & 15, lk = lane >> 4;

    f32x4 acc[4][4];
#pragma unroll
    for (int m = 0; m < 4; ++m)
#pragma unroll
        for (int n = 0; n < 4; ++n) acc[m][n] = (f32x4){0.f, 0.f, 0.f, 0.f};

    int arow = tid >> 1, as0 = (tid & 1) * 16;
    int arr = (r0 + arow < n_e) ? arow : 0;
    const unsigned short* abase = hbuf + (size_t)(p0 + arr) * HPAD;
    int brow = tid >> 1, bs0 = (tid & 1) * 16;
    const unsigned short* bbase = w3t + ((size_t)e * 1024 + d0 + brow) * HPAD;

#pragma unroll 1
    for (int k0 = 0; k0 < HPAD; k0 += 32) {
        us8 a0 = *(const us8*)(abase + k0 + as0);
        us8 a1 = *(const us8*)(abase + k0 + as0 + 8);
        us8 b0 = *(const us8*)(bbase + k0 + bs0);
        us8 b1 = *(const us8*)(bbase + k0 + bs0 + 8);
        __syncthreads();
        *(us8*)&Al[arow][as0] = a0;
        *(us8*)&Al[arow][as0 + 8] = a1;
        *(us8*)&Bl[brow][bs0] = b0;
        *(us8*)&Bl[brow][bs0 + 8] = b1;
        __syncthreads();
        bf16x8 af[4], bf_[4];
#pragma unroll
        for (int m = 0; m < 4; ++m)
            af[m] = *(const bf16x8*)&Al[wm * 64 + m * 16 + lr][lk * 8];
#pragma unroll
        for (int n = 0; n < 4; ++n)
            bf_[n] = *(const bf16x8*)&Bl[wn * 64 + n * 16 + lr][lk * 8];
#pragma unroll
        for (int m = 0; m < 4; ++m)
#pragma unroll
            for (int n = 0; n < 4; ++n)
                acc[m][n] = __builtin_amdgcn_mfma_f32_16x16x32_bf16(
                    af[m], bf_[n], acc[m][n], 0, 0, 0);
    }

#pragma unroll
    for (int m = 0; m < 4; ++m) {
        int rl0 = wm * 64 + m * 16 + lk * 4;
        // per-thread row metadata (4 rows per m)
#pragma unroll
        for (int q = 0; q < 4; ++q) {
            int rl = rl0 + q;
            if (r0 + rl < n_e) {
                int pp = p0 + rl;
                int tok = ptok[pp];
                float w = pw[pp];
                float* orow = out + (size_t)tok * DIMD + d0;
#pragma unroll
                for (int n = 0; n < 4; ++n) {
                    atomicAdd(orow + (wn * 64 + n * 16 + lr), w * acc[m][n][q]);
                }
            }
        }
    }
}

extern "C" void kernel_launch(void* const* d_in, const int* in_sizes, int n_in,
                              void* d_out, int out_size, void* d_ws, size_t ws_size,
                              hipStream_t stream) {
    const float* x   = (const float*)d_in[0];
    const float* wr  = (const float*)d_in[1];
    const float* w12 = (const float*)d_in[2];
    const float* w3  = (const float*)d_in[3];
    float* out = (float*)d_out;

    char* ws = (char*)d_ws;
    int*            ctrl = (int*)(ws + WS_CTRL);
    int*            topi = (int*)(ws + WS_TOPI);
    float*          topw = (float*)(ws + WS_TOPW);
    float*          pw   = (float*)(ws + WS_PW);
    int*            ptok = (int*)(ws + WS_PTOK);
    unsigned short* xb   = (unsigned short*)(ws + WS_XB);
    unsigned short* w12t = (unsigned short*)(ws + WS_W12T);
    unsigned short* w3t  = (unsigned short*)(ws + WS_W3T);
    unsigned short* hbuf = (unsigned short*)(ws + WS_HBUF);

    (void)ws_size; (void)in_sizes; (void)n_in; (void)out_size;

    (void)hipMemsetAsync(ctrl, 0, 256, stream);
    (void)hipMemsetAsync(out, 0, (size_t)T_TOK * DIMD * sizeof(float), stream);
    k_router<<<2048, 256, 0, stream>>>((const float4*)x, wr, (ushort4*)xb, topi, topw, ctrl);
    k_cvt_w12t<<<dim3(86, 32, 8), 256, 0, stream>>>(w12, w12t);
    k_cvt_w3t<<<dim3(86, 16, 8), 256, 0, stream>>>(w3, w3t);
    k_scan<<<1, 64, 0, stream>>>(ctrl);
    k_compact<<<32, 256, 0, stream>>>(topi, topw, ctrl, ptok, pw);
    k_gemm1<<<dim3(43, 64, 8), 256, 0, stream>>>(xb, w12t, ctrl, ptok, hbuf);
    k_gemm2<<<dim3(8, 64, 8), 256, 0, stream>>>(hbuf, w3t, ctrl, ptok, pw, out);
}

// Round 6
// 847.747 us; speedup vs baseline: 1.3390x; 1.1096x over previous
//
#include <hip/hip_runtime.h>

// ---------------------------------------------------------------------------
// MoE forward (top-2 of 8 experts), sparse-routed, bf16 MFMA.
// Round 6 = round-5 pipeline
//         + coalesced-write weight conversions (128B-contiguous k-fastest)
//         + BK=64 GEMM bodies (half the barrier rounds, same math order).
// ---------------------------------------------------------------------------

typedef __bf16 bf16x8 __attribute__((ext_vector_type(8)));
typedef float f32x4 __attribute__((ext_vector_type(4)));
typedef unsigned short us8 __attribute__((ext_vector_type(8)));

#define T_TOK 8192
#define DIMD 1024
#define NEXP 8
#define HID 2730
#define HPAD 2752
#define H2PAD 5504
#define NPAIR 16384

#define WS_CTRL  ((size_t)0)
#define WS_TOPI  ((size_t)256)
#define WS_TOPW  (WS_TOPI + 65536)
#define WS_PW    (WS_TOPW + 65536)
#define WS_PTOK  (WS_PW + 65536)
#define WS_XB    (WS_PTOK + 65536)
#define WS_W12T  (WS_XB + (size_t)16777216)
#define WS_W3T   (WS_W12T + (size_t)90177536)
#define WS_HBUF  (WS_W3T + (size_t)45088768)

__device__ __forceinline__ unsigned short f2bf(float f) {
    unsigned int u = __float_as_uint(f);
    u += 0x7fffu + ((u >> 16) & 1u);
    return (unsigned short)(u >> 16);
}

// ---------------- W12 -> bf16, transposed [e][half][jp(2752)][k(1024)] ------
// tile: 128 k x 32 j. Phase1: j-coalesced float2 reads. Phase2: k-fastest
// us8 writes (8 lanes = 128B contiguous cacheline).
__global__ void k_cvt_w12t(const float* __restrict__ w12, unsigned short* __restrict__ w12t) {
    int jt = blockIdx.x;              // 0..171
    int kt = blockIdx.y;              // 0..7
    int e  = blockIdx.z;
    int half = jt / 86, jt2 = jt % 86;
    int jh0 = jt2 * 32, k0 = kt * 128;
    __shared__ float tile[32][133];   // [j][k]
    int t = threadIdx.x;
    {
        int lane_j = t & 15, krow = t >> 4;
#pragma unroll
        for (int p = 0; p < 8; ++p) {
            int kk = p * 16 + krow;
            int j = jh0 + lane_j * 2;
            float2 v = make_float2(0.f, 0.f);
            if (j < HID)  // 2730 even -> float2 never straddles the boundary
                v = *(const float2*)(w12 + (size_t)(e * 1024 + k0 + kk) * 5460 + half * HID + j);
            tile[lane_j * 2][kk] = v.x;
            tile[lane_j * 2 + 1][kk] = v.y;
        }
    }
    __syncthreads();
    {
        int jj = t >> 3, kc = t & 7;
        unsigned short* dst = w12t + ((size_t)e * H2PAD + half * HPAD + jh0 + jj) * 1024 + k0;
#pragma unroll
        for (int cc = 0; cc < 2; ++cc) {
            int c = kc + cc * 8;
            us8 v;
#pragma unroll
            for (int b = 0; b < 8; ++b) v[b] = f2bf(tile[jj][c * 8 + b]);
            *(us8*)(dst + c * 8) = v;
        }
    }
}

// ---------------- W3 -> bf16, transposed [e][d(1024)][k(2752)] --------------
__global__ void k_cvt_w3t(const float* __restrict__ w3, unsigned short* __restrict__ w3t) {
    int kt = blockIdx.x;              // 0..21
    int dt = blockIdx.y;              // 0..31
    int e  = blockIdx.z;
    int k0 = kt * 128, d0 = dt * 32;
    __shared__ float tile[32][133];   // [d][k]
    int t = threadIdx.x;
    {
        int lane_d = t & 15, krow = t >> 4;
#pragma unroll
        for (int p = 0; p < 8; ++p) {
            int kk = k0 + p * 16 + krow;
            float2 v = make_float2(0.f, 0.f);
            if (kk < HID)
                v = *(const float2*)(w3 + (size_t)(e * HID + kk) * 1024 + d0 + lane_d * 2);
            tile[lane_d * 2][p * 16 + krow] = v.x;
            tile[lane_d * 2 + 1][p * 16 + krow] = v.y;
        }
    }
    __syncthreads();
    {
        int dd = t >> 3, kc = t & 7;
        unsigned short* dst = w3t + ((size_t)e * 1024 + d0 + dd) * HPAD + k0;
#pragma unroll
        for (int cc = 0; cc < 2; ++cc) {
            int c = kc + cc * 8;
            if (k0 + c * 8 < HPAD) {
                us8 v;
#pragma unroll
                for (int b = 0; b < 8; ++b) v[b] = f2bf(tile[dd][c * 8 + b]);
                *(us8*)(dst + c * 8) = v;
            }
        }
    }
}

// ---------------- router (fused x->bf16): fp64 logits, stable top-2 ---------
__global__ void k_router(const float4* __restrict__ x4, const float* __restrict__ wr,
                         ushort4* __restrict__ xb4,
                         int* __restrict__ topi, float* __restrict__ topw,
                         int* __restrict__ ctrl) {
    int wid = threadIdx.x >> 6, lane = threadIdx.x & 63;
    int t = blockIdx.x * 4 + wid;
    const float4* xr = x4 + (size_t)t * 256;
    double acc[NEXP];
#pragma unroll
    for (int e = 0; e < NEXP; ++e) acc[e] = 0.0;
#pragma unroll
    for (int it = 0; it < 4; ++it) {
        int d4 = it * 64 + lane;
        float4 v = xr[d4];
        ushort4 r;
        r.x = f2bf(v.x); r.y = f2bf(v.y); r.z = f2bf(v.z); r.w = f2bf(v.w);
        xb4[(size_t)t * 256 + d4] = r;
        const float* w = wr + (size_t)d4 * 4 * NEXP;
#pragma unroll
        for (int e = 0; e < NEXP; ++e) {
            acc[e] += (double)v.x * (double)w[e]
                    + (double)v.y * (double)w[NEXP + e]
                    + (double)v.z * (double)w[2 * NEXP + e]
                    + (double)v.w * (double)w[3 * NEXP + e];
        }
    }
#pragma unroll
    for (int e = 0; e < NEXP; ++e) {
        for (int off = 32; off > 0; off >>= 1) acc[e] += __shfl_down(acc[e], off);
    }
    if (lane == 0) {
        double b0 = -1e300, b1 = -1e300; int i0 = 0, i1 = 0;
#pragma unroll
        for (int e = 0; e < NEXP; ++e) {
            double v = acc[e];
            if (v > b0) { b1 = b0; i1 = i0; b0 = v; i0 = e; }
            else if (v > b1) { b1 = v; i1 = e; }
        }
        float e1 = expf((float)(b1 - b0));
        float w0 = 1.0f / (1.0f + e1);
        float w1 = e1 / (1.0f + e1);
        topi[2 * t] = i0; topi[2 * t + 1] = i1;
        topw[2 * t] = w0; topw[2 * t + 1] = w1;
        atomicAdd(&ctrl[i0], 1);
        atomicAdd(&ctrl[i1], 1);
    }
}

__global__ void k_scan(int* ctrl) {
    if (threadIdx.x == 0 && blockIdx.x == 0) {
        int s = 0;
        for (int e = 0; e < NEXP; ++e) { ctrl[16 + e] = s; s += ctrl[e]; }
        ctrl[16 + NEXP] = s;
    }
}

__global__ void k_compact(const int* __restrict__ topi, const float* __restrict__ topw,
                          int* __restrict__ ctrl,
                          int* __restrict__ ptok, float* __restrict__ pw) {
    int t = blockIdx.x * 256 + threadIdx.x;
    if (t >= T_TOK) return;
#pragma unroll
    for (int k = 0; k < 2; ++k) {
        int e = topi[2 * t + k];
        int p = ctrl[16 + e] + atomicAdd(&ctrl[8 + e], 1);
        ptok[p] = t;
        pw[p] = topw[2 * t + k];
    }
}

// ---------------- GEMM1 + GLU: h = silu(x@W1)*(x@W2), bf16 out --------------
// block: 128 rows x 64 h-cols (both halves), BK=64, 4 waves (2m x 2n)
// grid: x = j-tile(43) fastest (proven r2 order)
__global__ __launch_bounds__(256, 2) void k_gemm1(
    const unsigned short* __restrict__ xb,
    const unsigned short* __restrict__ w12t,
    const int* __restrict__ ctrl,
    const int* __restrict__ ptok,
    unsigned short* __restrict__ hbuf) {
    int e = blockIdx.z;
    int n_e = ctrl[e];
    int r0 = blockIdx.y * 128;
    if (r0 >= n_e) return;
    int p0 = ctrl[16 + e] + r0;
    int j0 = blockIdx.x * 64;

    __shared__ unsigned short Al[128][72];
    __shared__ unsigned short Bl[2][64][72];
    __shared__ int stok[128];

    int tid = threadIdx.x;
    if (tid < 128) {
        stok[tid] = (r0 + tid < n_e) ? ptok[p0 + tid] : 0;
    }
    __syncthreads();

    int lane = tid & 63, wid = tid >> 6;
    int wm = wid >> 1, wn = wid & 1;
    int lr = lane & 15, lk = lane >> 4;

    f32x4 acc[2][4][2];
#pragma unroll
    for (int h = 0; h < 2; ++h)
#pragma unroll
        for (int m = 0; m < 4; ++m)
#pragma unroll
            for (int n = 0; n < 2; ++n) acc[h][m][n] = (f32x4){0.f, 0.f, 0.f, 0.f};

    int arow = tid >> 1, as0 = (tid & 1) * 32;
    const unsigned short* abase = xb + (size_t)stok[arow] * DIMD;
    int bhjj = tid >> 1;
    int bh = bhjj >> 6, bjj = bhjj & 63, bs0 = (tid & 1) * 32;
    const unsigned short* bbase = w12t + ((size_t)e * H2PAD + bh * HPAD + j0 + bjj) * 1024;

#pragma unroll 1
    for (int k0 = 0; k0 < DIMD; k0 += 64) {
        us8 a0 = *(const us8*)(abase + k0 + as0);
        us8 a1 = *(const us8*)(abase + k0 + as0 + 8);
        us8 a2 = *(const us8*)(abase + k0 + as0 + 16);
        us8 a3 = *(const us8*)(abase + k0 + as0 + 24);
        us8 b0 = *(const us8*)(bbase + k0 + bs0);
        us8 b1 = *(const us8*)(bbase + k0 + bs0 + 8);
        us8 b2 = *(const us8*)(bbase + k0 + bs0 + 16);
        us8 b3 = *(const us8*)(bbase + k0 + bs0 + 24);
        __syncthreads();
        *(us8*)&Al[arow][as0] = a0;
        *(us8*)&Al[arow][as0 + 8] = a1;
        *(us8*)&Al[arow][as0 + 16] = a2;
        *(us8*)&Al[arow][as0 + 24] = a3;
        *(us8*)&Bl[bh][bjj][bs0] = b0;
        *(us8*)&Bl[bh][bjj][bs0 + 8] = b1;
        *(us8*)&Bl[bh][bjj][bs0 + 16] = b2;
        *(us8*)&Bl[bh][bjj][bs0 + 24] = b3;
        __syncthreads();
#pragma unroll
        for (int ks = 0; ks < 2; ++ks) {
            bf16x8 af[4];
#pragma unroll
            for (int m = 0; m < 4; ++m)
                af[m] = *(const bf16x8*)&Al[wm * 64 + m * 16 + lr][ks * 32 + lk * 8];
            bf16x8 bf_[2][2];
#pragma unroll
            for (int h = 0; h < 2; ++h)
#pragma unroll
                for (int n = 0; n < 2; ++n)
                    bf_[h][n] = *(const bf16x8*)&Bl[h][wn * 32 + n * 16 + lr][ks * 32 + lk * 8];
#pragma unroll
            for (int h = 0; h < 2; ++h)
#pragma unroll
                for (int m = 0; m < 4; ++m)
#pragma unroll
                    for (int n = 0; n < 2; ++n)
                        acc[h][m][n] = __builtin_amdgcn_mfma_f32_16x16x32_bf16(
                            af[m], bf_[h][n], acc[h][m][n], 0, 0, 0);
        }
        __syncthreads();
    }

#pragma unroll
    for (int m = 0; m < 4; ++m)
#pragma unroll
        for (int n = 0; n < 2; ++n)
#pragma unroll
            for (int q = 0; q < 4; ++q) {
                int rl = wm * 64 + m * 16 + lk * 4 + q;
                if (r0 + rl < n_e) {
                    float v1 = acc[0][m][n][q];
                    float v2 = acc[1][m][n][q];
                    float hv = v1 * (1.0f / (1.0f + __expf(-v1))) * v2;
                    hbuf[(size_t)(p0 + rl) * HPAD + (j0 + wn * 32 + n * 16 + lr)] = f2bf(hv);
                }
            }
}

// ---------------- GEMM2 + gated scatter-add: out[tok] += w * (h @ W3) -------
// block: 128 rows x 128 d-cols, BK=64, 4 waves (2m x 2n), K=2752 (43 rounds)
__global__ __launch_bounds__(256, 2) void k_gemm2(
    const unsigned short* __restrict__ hbuf,
    const unsigned short* __restrict__ w3t,
    const int* __restrict__ ctrl,
    const int* __restrict__ ptok,
    const float* __restrict__ pw,
    float* __restrict__ out) {
    int e = blockIdx.z;
    int n_e = ctrl[e];
    int r0 = blockIdx.y * 128;
    if (r0 >= n_e) return;
    int p0 = ctrl[16 + e] + r0;
    int d0 = blockIdx.x * 128;

    __shared__ unsigned short Al[128][72];
    __shared__ unsigned short Bl[128][72];

    int tid = threadIdx.x;
    int lane = tid & 63, wid = tid >> 6;
    int wm = wid >> 1, wn = wid & 1;
    int lr = lane & 15, lk = lane >> 4;

    f32x4 acc[4][4];
#pragma unroll
    for (int m = 0; m < 4; ++m)
#pragma unroll
        for (int n = 0; n < 4; ++n) acc[m][n] = (f32x4){0.f, 0.f, 0.f, 0.f};

    int arow = tid >> 1, as0 = (tid & 1) * 32;
    int arr = (r0 + arow < n_e) ? arow : 0;
    const unsigned short* abase = hbuf + (size_t)(p0 + arr) * HPAD;
    int brow = tid >> 1, bs0 = (tid & 1) * 32;
    const unsigned short* bbase = w3t + ((size_t)e * 1024 + d0 + brow) * HPAD;

#pragma unroll 1
    for (int k0 = 0; k0 < HPAD; k0 += 64) {
        us8 a0 = *(const us8*)(abase + k0 + as0);
        us8 a1 = *(const us8*)(abase + k0 + as0 + 8);
        us8 a2 = *(const us8*)(abase + k0 + as0 + 16);
        us8 a3 = *(const us8*)(abase + k0 + as0 + 24);
        us8 b0 = *(const us8*)(bbase + k0 + bs0);
        us8 b1 = *(const us8*)(bbase + k0 + bs0 + 8);
        us8 b2 = *(const us8*)(bbase + k0 + bs0 + 16);
        us8 b3 = *(const us8*)(bbase + k0 + bs0 + 24);
        __syncthreads();
        *(us8*)&Al[arow][as0] = a0;
        *(us8*)&Al[arow][as0 + 8] = a1;
        *(us8*)&Al[arow][as0 + 16] = a2;
        *(us8*)&Al[arow][as0 + 24] = a3;
        *(us8*)&Bl[brow][bs0] = b0;
        *(us8*)&Bl[brow][bs0 + 8] = b1;
        *(us8*)&Bl[brow][bs0 + 16] = b2;
        *(us8*)&Bl[brow][bs0 + 24] = b3;
        __syncthreads();
#pragma unroll
        for (int ks = 0; ks < 2; ++ks) {
            bf16x8 af[4], bf_[4];
#pragma unroll
            for (int m = 0; m < 4; ++m)
                af[m] = *(const bf16x8*)&Al[wm * 64 + m * 16 + lr][ks * 32 + lk * 8];
#pragma unroll
            for (int n = 0; n < 4; ++n)
                bf_[n] = *(const bf16x8*)&Bl[wn * 64 + n * 16 + lr][ks * 32 + lk * 8];
#pragma unroll
            for (int m = 0; m < 4; ++m)
#pragma unroll
                for (int n = 0; n < 4; ++n)
                    acc[m][n] = __builtin_amdgcn_mfma_f32_16x16x32_bf16(
                        af[m], bf_[n], acc[m][n], 0, 0, 0);
        }
        __syncthreads();
    }

#pragma unroll
    for (int m = 0; m < 4; ++m) {
        int rl0 = wm * 64 + m * 16 + lk * 4;
#pragma unroll
        for (int q = 0; q < 4; ++q) {
            int rl = rl0 + q;
            if (r0 + rl < n_e) {
                int pp = p0 + rl;
                int tok = ptok[pp];
                float w = pw[pp];
                float* orow = out + (size_t)tok * DIMD + d0;
#pragma unroll
                for (int n = 0; n < 4; ++n) {
                    atomicAdd(orow + (wn * 64 + n * 16 + lr), w * acc[m][n][q]);
                }
            }
        }
    }
}

extern "C" void kernel_launch(void* const* d_in, const int* in_sizes, int n_in,
                              void* d_out, int out_size, void* d_ws, size_t ws_size,
                              hipStream_t stream) {
    const float* x   = (const float*)d_in[0];
    const float* wr  = (const float*)d_in[1];
    const float* w12 = (const float*)d_in[2];
    const float* w3  = (const float*)d_in[3];
    float* out = (float*)d_out;

    char* ws = (char*)d_ws;
    int*            ctrl = (int*)(ws + WS_CTRL);
    int*            topi = (int*)(ws + WS_TOPI);
    float*          topw = (float*)(ws + WS_TOPW);
    float*          pw   = (float*)(ws + WS_PW);
    int*            ptok = (int*)(ws + WS_PTOK);
    unsigned short* xb   = (unsigned short*)(ws + WS_XB);
    unsigned short* w12t = (unsigned short*)(ws + WS_W12T);
    unsigned short* w3t  = (unsigned short*)(ws + WS_W3T);
    unsigned short* hbuf = (unsigned short*)(ws + WS_HBUF);

    (void)ws_size; (void)in_sizes; (void)n_in; (void)out_size;

    (void)hipMemsetAsync(ctrl, 0, 256, stream);
    (void)hipMemsetAsync(out, 0, (size_t)T_TOK * DIMD * sizeof(float), stream);
    k_router<<<2048, 256, 0, stream>>>((const float4*)x, wr, (ushort4*)xb, topi, topw, ctrl);
    k_cvt_w12t<<<dim3(172, 8, 8), 256, 0, stream>>>(w12, w12t);
    k_cvt_w3t<<<dim3(22, 32, 8), 256, 0, stream>>>(w3, w3t);
    k_scan<<<1, 64, 0, stream>>>(ctrl);
    k_compact<<<32, 256, 0, stream>>>(topi, topw, ctrl, ptok, pw);
    k_gemm1<<<dim3(43, 64, 8), 256, 0, stream>>>(xb, w12t, ctrl, ptok, hbuf);
    k_gemm2<<<dim3(8, 64, 8), 256, 0, stream>>>(hbuf, w3t, ctrl, ptok, pw, out);
}